// Round 2
// baseline (958.962 us; speedup 1.0000x reference)
//
#include <hip/hip_runtime.h>
#include <hip/hip_bf16.h>

// NodeModelBase: per-edge MLP (Linear->LN->ReLU->Linear) + scatter_mean.
// R1: occupancy 1->2 waves/SIMD (512 blocks, launch_bounds(256,2)),
//     h2 stored pre-permuted by CSR rank (reduce streams sequentially),
//     LDS row rotation to break 8-way b128 read bank conflicts.

typedef __bf16 bf16x8 __attribute__((ext_vector_type(8)));
typedef float f32x4 __attribute__((ext_vector_type(4)));

#define LN_EPS 1e-5f

__device__ __forceinline__ unsigned short bfbits(float f) {
  return __builtin_bit_cast(unsigned short, (__bf16)f);
}
__device__ __forceinline__ float bflo(unsigned int u) { return __uint_as_float(u << 16); }
__device__ __forceinline__ float bfhi(unsigned int u) { return __uint_as_float(u & 0xffff0000u); }

// LDS layout: 16 rows x 256B, row r rotated by r*32 bytes (breaks the
// multiple-of-4 start-bank aliasing of 16B-aligned accesses; preserves 16B align)
__device__ __forceinline__ int swz(int row, int off) {
  return row * 256 + ((off + row * 32) & 255);
}

// ---------------------------------------------------------------- histogram
__global__ void hist_kernel(const int* __restrict__ eidx, int* __restrict__ cnt, int E) {
  int e = blockIdx.x * blockDim.x + threadIdx.x;
  if (e < E) atomicAdd(&cnt[eidx[E + e]], 1);
}

// ------------------------------------------------------- exclusive scan (1 WG)
__global__ void scan_kernel(const int* __restrict__ cnt, int* __restrict__ off, int n) {
  __shared__ int wsum[16];
  __shared__ int carry_s;
  const int tid = threadIdx.x;
  const int wv = tid >> 6;
  const int ln = tid & 63;
  if (tid == 0) carry_s = 0;
  __syncthreads();
  for (int base = 0; base < n; base += 4096) {
    int i0 = base + tid * 4;
    int a = (i0 < n) ? cnt[i0] : 0;
    int b = (i0 + 1 < n) ? cnt[i0 + 1] : 0;
    int c = (i0 + 2 < n) ? cnt[i0 + 2] : 0;
    int d = (i0 + 3 < n) ? cnt[i0 + 3] : 0;
    int lsum = a + b + c + d;
    int sc = lsum;
#pragma unroll
    for (int dl = 1; dl < 64; dl <<= 1) {
      int t = __shfl_up(sc, dl);
      if (ln >= dl) sc += t;
    }
    if (ln == 63) wsum[wv] = sc;
    __syncthreads();
    int woff = 0;
#pragma unroll
    for (int w = 0; w < 16; ++w) {
      int t = wsum[w];
      if (w < wv) woff += t;
    }
    int excl = carry_s + woff + sc - lsum;
    if (i0 < n) off[i0] = excl;
    if (i0 + 1 < n) off[i0 + 1] = excl + a;
    if (i0 + 2 < n) off[i0 + 2] = excl + a + b;
    if (i0 + 3 < n) off[i0 + 3] = excl + a + b + c;
    __syncthreads();
    if (tid == 1023) carry_s = carry_s + woff + sc;
    __syncthreads();
  }
}

// --------------------------------------------- rank assignment (CSR position)
__global__ void rank_kernel(const int* __restrict__ eidx, const int* __restrict__ off,
                            int* __restrict__ cur, int* __restrict__ rank, int E) {
  int e = blockIdx.x * blockDim.x + threadIdx.x;
  if (e < E) {
    int c = eidx[E + e];
    int p = atomicAdd(&cur[c], 1);
    rank[e] = off[c] + p;
  }
}

// ----------------------------------------------------------------- main MLP
// Per 16-edge tile, per wave:
//   GEMM1: D1[n1][e] = sum_k W1[k][n1] * feat[e][k]   (A = W1^T frags in regs,
//          B = features loaded straight from global as 8-consecutive-k frags)
//   LN over n1 (lane holds 32 vals of ONE edge; 2 shfl_xor finish the stats)
//   LDS round-trip to convert C-layout -> B-operand layout for GEMM2
//   GEMM2: D2[n2][e] = sum_k W2[k][n2] * hrelu[e][k]
//   Epilogue: coalesced bf16 store of h2 rows at CSR rank (two-phase path)
//             or fp32 atomic scatter into out (fallback path).
template <bool ATOMIC>
__global__ __launch_bounds__(256, 2) void mlp_kernel(
    const float* __restrict__ x, const float* __restrict__ ea,
    const int* __restrict__ eidx, const int* __restrict__ rank,
    const float* __restrict__ W1, const float* __restrict__ b1,
    const float* __restrict__ lng, const float* __restrict__ lnb,
    const float* __restrict__ W2, const float* __restrict__ b2,
    float* __restrict__ out, unsigned short* __restrict__ h2, int E, int ntiles) {
  __shared__ __align__(16) char hbuf[4][16 * 256];
  const int tid = threadIdx.x;
  const int lane = tid & 63;
  const int wv = tid >> 6;
  const int e15 = lane & 15;
  const int q = lane >> 4;
  char* hb = hbuf[wv];

  // ---- prologue: W1/W2 as A-operand fragments, register resident ----
  // A[m][k]: m = lane&15 (+16*mt) = output feature n, k = q*8+j (+32*ks)
  bf16x8 w1f[4][8], w2f[4][8];
#pragma unroll
  for (int ks = 0; ks < 4; ++ks) {
#pragma unroll
    for (int mt = 0; mt < 8; ++mt) {
      bf16x8 a1, a2;
#pragma unroll
      for (int j = 0; j < 8; ++j) {
        int k = ks * 32 + q * 8 + j;
        int n = mt * 16 + e15;
        a1[j] = (__bf16)W1[k * 128 + n];
        a2[j] = (__bf16)W2[k * 128 + n];
      }
      w1f[ks][mt] = a1;
      w2f[ks][mt] = a2;
    }
  }
  // per-lane constants for C/D rows n = mt*16 + q*4 + r
  f32x4 b1c[8], b2c[8];
  unsigned int glc[8][4];  // low16 = bf16(ln_g), high16 = bf16(ln_b)
#pragma unroll
  for (int mt = 0; mt < 8; ++mt) {
#pragma unroll
    for (int r = 0; r < 4; ++r) {
      int n = mt * 16 + q * 4 + r;
      b1c[mt][r] = b1[n];
      b2c[mt][r] = b2[n];
      glc[mt][r] = (unsigned int)__builtin_bit_cast(unsigned short, (__bf16)lng[n]) |
                   ((unsigned int)__builtin_bit_cast(unsigned short, (__bf16)lnb[n]) << 16);
    }
  }

  const int nwav = (gridDim.x * blockDim.x) >> 6;
  const int wid = (blockIdx.x * blockDim.x + tid) >> 6;

  for (int t = wid; t < ntiles; t += nwav) {
    const int e = t * 16 + e15;
    const int row = eidx[e];
    const float* xr = x + (size_t)row * 64;
    const float* ar = ea + (size_t)e * 64;
    float4 raw[4][2];
    raw[0][0] = *(const float4*)(xr + q * 8);
    raw[0][1] = *(const float4*)(xr + q * 8 + 4);
    raw[1][0] = *(const float4*)(xr + 32 + q * 8);
    raw[1][1] = *(const float4*)(xr + 32 + q * 8 + 4);
    raw[2][0] = *(const float4*)(ar + q * 8);
    raw[2][1] = *(const float4*)(ar + q * 8 + 4);
    raw[3][0] = *(const float4*)(ar + 32 + q * 8);
    raw[3][1] = *(const float4*)(ar + 32 + q * 8 + 4);
    bf16x8 bfr[4];
#pragma unroll
    for (int ks = 0; ks < 4; ++ks) {
      const float* p0 = (const float*)&raw[ks][0];
      const float* p1 = (const float*)&raw[ks][1];
#pragma unroll
      for (int j = 0; j < 4; ++j) {
        bfr[ks][j] = (__bf16)p0[j];
        bfr[ks][4 + j] = (__bf16)p1[j];
      }
    }
    f32x4 c1[8];
#pragma unroll
    for (int mt = 0; mt < 8; ++mt) c1[mt] = b1c[mt];
#pragma unroll
    for (int ks = 0; ks < 4; ++ks)
#pragma unroll
      for (int mt = 0; mt < 8; ++mt)
        c1[mt] = __builtin_amdgcn_mfma_f32_16x16x32_bf16(w1f[ks][mt], bfr[ks], c1[mt], 0, 0, 0);

    // ---- LayerNorm over 128 features of edge e (lanes e15, e15+16, +32, +48)
    float s = 0.f, ss = 0.f;
#pragma unroll
    for (int mt = 0; mt < 8; ++mt)
#pragma unroll
      for (int r = 0; r < 4; ++r) {
        float v = c1[mt][r];
        s += v;
        ss += v * v;
      }
    s += __shfl_xor(s, 16);
    s += __shfl_xor(s, 32);
    ss += __shfl_xor(ss, 16);
    ss += __shfl_xor(ss, 32);
    const float mu = s * 0.0078125f;
    const float var = ss * 0.0078125f - mu * mu;
    const float inv = rsqrtf(var + LN_EPS);
#pragma unroll
    for (int mt = 0; mt < 8; ++mt) {
      unsigned short u[4];
#pragma unroll
      for (int r = 0; r < 4; ++r) {
        float v = (c1[mt][r] - mu) * inv;
        unsigned int g = glc[mt][r];
        v = v * bflo(g) + bfhi(g);
        v = fmaxf(v, 0.f);
        u[r] = bfbits(v);
      }
      uint2 w;
      w.x = (unsigned int)u[0] | ((unsigned int)u[1] << 16);
      w.y = (unsigned int)u[2] | ((unsigned int)u[3] << 16);
      // h[e][n1], n1 = mt*16 + q*4 + r  (C-layout rows are 4-consecutive -> b64)
      *(uint2*)(hb + swz(e15, mt * 32 + q * 8)) = w;
    }
    // ---- reload as B-operand frags: B[k][e], k = ks*32 + q*8 + j
    bf16x8 hf[4];
#pragma unroll
    for (int ks = 0; ks < 4; ++ks)
      hf[ks] = __builtin_bit_cast(bf16x8, *(const uint4*)(hb + swz(e15, ks * 64 + q * 16)));
    f32x4 c2[8];
#pragma unroll
    for (int mt = 0; mt < 8; ++mt) c2[mt] = b2c[mt];
#pragma unroll
    for (int ks = 0; ks < 4; ++ks)
#pragma unroll
      for (int mt = 0; mt < 8; ++mt)
        c2[mt] = __builtin_amdgcn_mfma_f32_16x16x32_bf16(w2f[ks][mt], hf[ks], c2[mt], 0, 0, 0);

    if constexpr (ATOMIC) {
      const int cl = eidx[E + e];
      float* op = out + (size_t)cl * 128 + q * 4;
#pragma unroll
      for (int mt = 0; mt < 8; ++mt)
#pragma unroll
        for (int r = 0; r < 4; ++r) unsafeAtomicAdd(op + mt * 16 + r, c2[mt][r]);
    } else {
      // stage bf16 h2 rows in LDS, then coalesced 16B stores at CSR rank
#pragma unroll
      for (int mt = 0; mt < 8; ++mt) {
        unsigned short u[4];
#pragma unroll
        for (int r = 0; r < 4; ++r) u[r] = bfbits(c2[mt][r]);
        uint2 w;
        w.x = (unsigned int)u[0] | ((unsigned int)u[1] << 16);
        w.y = (unsigned int)u[2] | ((unsigned int)u[3] << 16);
        *(uint2*)(hb + swz(e15, mt * 32 + q * 8)) = w;
      }
      const int r0 = lane >> 2, c0 = lane & 3;
      const int rk = rank[t * 16 + r0];
#pragma unroll
      for (int i = 0; i < 4; ++i) {
        uint4 v = *(const uint4*)(hb + swz(r0, (c0 + 4 * i) * 16));
        *(uint4*)((char*)h2 + (size_t)rk * 256 + (c0 + 4 * i) * 16) = v;
      }
    }
  }
}

// ------------------------------------- segmented mean (h2 already CSR-sorted)
__global__ void reduce_kernel(const unsigned short* __restrict__ h2,
                              const int* __restrict__ off, const int* __restrict__ cnt,
                              float* __restrict__ out, int N) {
  int tid = blockIdx.x * blockDim.x + threadIdx.x;
  int node = tid >> 4;  // 16 lanes per node, 8 features each
  if (node >= N) return;
  int sub = tid & 15;
  int deg = cnt[node];
  int start = off[node];
  float acc[8] = {0.f, 0.f, 0.f, 0.f, 0.f, 0.f, 0.f, 0.f};
  const unsigned short* p = h2 + (size_t)start * 128 + sub * 8;
  for (int j = 0; j < deg; ++j, p += 128) {
    uint4 v = *(const uint4*)p;
    acc[0] += bflo(v.x);
    acc[1] += bfhi(v.x);
    acc[2] += bflo(v.y);
    acc[3] += bfhi(v.y);
    acc[4] += bflo(v.z);
    acc[5] += bfhi(v.z);
    acc[6] += bflo(v.w);
    acc[7] += bfhi(v.w);
  }
  float sc = 1.f / (float)(deg > 0 ? deg : 1);
  float* op = out + (size_t)node * 128 + sub * 8;
  float4 o;
  o.x = acc[0] * sc;
  o.y = acc[1] * sc;
  o.z = acc[2] * sc;
  o.w = acc[3] * sc;
  *(float4*)op = o;
  o.x = acc[4] * sc;
  o.y = acc[5] * sc;
  o.z = acc[6] * sc;
  o.w = acc[7] * sc;
  *(float4*)(op + 4) = o;
}

// ------------------------------------------------------ divide (atomic path)
__global__ void divide_kernel(float* __restrict__ out, const int* __restrict__ cnt, int N) {
  int i = blockIdx.x * blockDim.x + threadIdx.x;
  if (i >= N * 32) return;  // N*128/4 float4s
  int node = i >> 5;
  float s = 1.f / (float)(cnt[node] > 0 ? cnt[node] : 1);
  float4* p = (float4*)out + i;
  float4 v = *p;
  v.x *= s;
  v.y *= s;
  v.z *= s;
  v.w *= s;
  *p = v;
}

extern "C" void kernel_launch(void* const* d_in, const int* in_sizes, int n_in,
                              void* d_out, int out_size, void* d_ws, size_t ws_size,
                              hipStream_t stream) {
  const float* x = (const float*)d_in[0];
  const float* ea = (const float*)d_in[1];
  const int* eidx = (const int*)d_in[2];
  const float* W1 = (const float*)d_in[3];
  const float* b1 = (const float*)d_in[4];
  const float* lng = (const float*)d_in[5];
  const float* lnb = (const float*)d_in[6];
  const float* W2 = (const float*)d_in[7];
  const float* b2 = (const float*)d_in[8];
  float* out = (float*)d_out;

  const int N = in_sizes[0] / 64;   // 50000
  const int E = in_sizes[1] / 64;   // 800000
  const int ntiles = E / 16;
  const size_t h2B = (size_t)E * 256;   // bf16 h2 rows
  const size_t rankB = (size_t)E * 4;
  const size_t cB = (size_t)N * 4;
  const size_t need = h2B + rankB + 3 * cB;
  const int eblocks = (E + 255) / 256;

  if (ws_size >= need) {
    // ---- two-phase CSR path: h2 stored pre-permuted, streaming reduce ----
    unsigned short* h2 = (unsigned short*)d_ws;
    char* base = (char*)d_ws + h2B;
    int* rank = (int*)base;
    int* cnt = (int*)(base + rankB);
    int* cur = (int*)(base + rankB + cB);
    int* off = (int*)(base + rankB + 2 * cB);
    hipMemsetAsync(cnt, 0, 2 * cB, stream);  // cnt + cur contiguous
    hist_kernel<<<eblocks, 256, 0, stream>>>(eidx, cnt, E);
    scan_kernel<<<1, 1024, 0, stream>>>(cnt, off, N);
    rank_kernel<<<eblocks, 256, 0, stream>>>(eidx, off, cur, rank, E);
    mlp_kernel<false><<<512, 256, 0, stream>>>(x, ea, eidx, rank, W1, b1, lng, lnb, W2, b2,
                                               out, h2, E, ntiles);
    reduce_kernel<<<(N * 16 + 255) / 256, 256, 0, stream>>>(h2, off, cnt, out, N);
  } else {
    // ---- fallback: fused atomic scatter (needs only N*4 bytes of ws) ----
    int* cnt = (int*)d_ws;
    hipMemsetAsync(out, 0, (size_t)out_size * 4, stream);
    hipMemsetAsync(cnt, 0, cB, stream);
    hist_kernel<<<eblocks, 256, 0, stream>>>(eidx, cnt, E);
    mlp_kernel<true><<<512, 256, 0, stream>>>(x, ea, eidx, nullptr, W1, b1, lng, lnb, W2, b2,
                                              out, (unsigned short*)d_ws, E, ntiles);
    divide_kernel<<<(N * 32 + 255) / 256, 256, 0, stream>>>(out, cnt, N);
  }
}

// Round 3
// 878.324 us; speedup vs baseline: 1.0918x; 1.0918x over previous
//
#include <hip/hip_runtime.h>
#include <hip/hip_bf16.h>

// NodeModelBase: per-edge MLP (Linear->LN->ReLU->Linear) + scatter_mean.
// R2: weights staged ONCE into LDS in MFMA A-frag layout (R0/R1 silently
//     re-loaded/spilled them: 256 VGPRs of weights never fit). 512-thread
//     blocks, 8 waves/CU, no spill. ET=2 tiles/iter. Hierarchical scan.
//     Wave-per-node streaming reduce.

typedef __bf16 bf16x8 __attribute__((ext_vector_type(8)));
typedef float f32x4 __attribute__((ext_vector_type(4)));

#define LN_EPS 1e-5f

__device__ __forceinline__ unsigned short bfbits(float f) {
  return __builtin_bit_cast(unsigned short, (__bf16)f);
}
__device__ __forceinline__ float bflo(unsigned int u) { return __uint_as_float(u << 16); }
__device__ __forceinline__ float bfhi(unsigned int u) { return __uint_as_float(u & 0xffff0000u); }

// ---------------------------------------------------------------- histogram
__global__ void hist_kernel(const int* __restrict__ eidx, int* __restrict__ cnt, int E) {
  int e = blockIdx.x * blockDim.x + threadIdx.x;
  if (e < E) atomicAdd(&cnt[eidx[E + e]], 1);
}

// --------------------------------------------------- hierarchical scan (3 kernels)
__global__ void partial_kernel(const int* __restrict__ cnt, int* __restrict__ psum, int n) {
  int base = blockIdx.x * 1024 + threadIdx.x * 4;
  int s = 0;
#pragma unroll
  for (int i = 0; i < 4; ++i) {
    int idx = base + i;
    if (idx < n) s += cnt[idx];
  }
#pragma unroll
  for (int d = 1; d < 64; d <<= 1) s += __shfl_xor(s, d);
  __shared__ int ws[4];
  if ((threadIdx.x & 63) == 0) ws[threadIdx.x >> 6] = s;
  __syncthreads();
  if (threadIdx.x == 0) psum[blockIdx.x] = ws[0] + ws[1] + ws[2] + ws[3];
}

__global__ void scanp_kernel(int* __restrict__ psum, int nb) {  // 1 block, 64 thr, nb<=64
  int t = threadIdx.x;
  int v = (t < nb) ? psum[t] : 0;
  int sc = v;
#pragma unroll
  for (int d = 1; d < 64; d <<= 1) {
    int u = __shfl_up(sc, d);
    if (t >= d) sc += u;
  }
  if (t < nb) psum[t] = sc - v;  // exclusive
}

__global__ void scanout_kernel(const int* __restrict__ cnt, const int* __restrict__ psum,
                               int* __restrict__ off, int n) {
  int tid = threadIdx.x;
  int base = blockIdx.x * 1024 + tid * 4;
  int a = (base < n) ? cnt[base] : 0;
  int b = (base + 1 < n) ? cnt[base + 1] : 0;
  int c = (base + 2 < n) ? cnt[base + 2] : 0;
  int d = (base + 3 < n) ? cnt[base + 3] : 0;
  int lsum = a + b + c + d;
  int sc = lsum;
#pragma unroll
  for (int dl = 1; dl < 64; dl <<= 1) {
    int t = __shfl_up(sc, dl);
    if ((tid & 63) >= dl) sc += t;
  }
  __shared__ int ws[4];
  if ((tid & 63) == 63) ws[tid >> 6] = sc;
  __syncthreads();
  int woff = psum[blockIdx.x];
#pragma unroll
  for (int w = 0; w < 4; ++w) {
    int t = ws[w];
    if (w < (tid >> 6)) woff += t;
  }
  int excl = woff + sc - lsum;
  if (base < n) off[base] = excl;
  if (base + 1 < n) off[base + 1] = excl + a;
  if (base + 2 < n) off[base + 2] = excl + a + b;
  if (base + 3 < n) off[base + 3] = excl + a + b + c;
}

// --------------------------------------------- rank assignment (CSR position)
__global__ void rank_kernel(const int* __restrict__ eidx, const int* __restrict__ off,
                            int* __restrict__ cur, int* __restrict__ rank, int E) {
  int e = blockIdx.x * blockDim.x + threadIdx.x;
  if (e < E) {
    int c = eidx[E + e];
    int p = atomicAdd(&cur[c], 1);
    rank[e] = off[c] + p;
  }
}

// ----------------------------------------------------------------- main MLP
// Weights in LDS (A-frag layout, bf16, staged once per block).
// Per wave-iteration: 2 tiles of 16 edges. GEMM1 -> LN -> LDS relayout ->
// GEMM2 -> bf16 store at CSR rank (or fp32 atomics in fallback).
template <bool ATOMIC>
__global__ __launch_bounds__(512, 2) void mlp_kernel(
    const float* __restrict__ x, const float* __restrict__ ea,
    const int* __restrict__ eidx, const int* __restrict__ rank,
    const float* __restrict__ W1, const float* __restrict__ b1,
    const float* __restrict__ lng, const float* __restrict__ lnb,
    const float* __restrict__ W2, const float* __restrict__ b2,
    float* __restrict__ out, unsigned short* __restrict__ h2, int E, int ntiles) {
  // W1/W2 in A-frag layout: [g=ks*8+mt][lane][16B]  (32 KB each)
  __shared__ __align__(16) char wlds[2][32768];
  __shared__ __align__(16) float b1L[128];
  __shared__ __align__(16) float b2L[128];
  __shared__ __align__(16) unsigned int glcL[128];
  // per-wave, per-tile staging: 16 rows x 272B (pad breaks bank aliasing)
  __shared__ __align__(16) char hstage[16][16 * 272];

  const int tid = threadIdx.x;
  const int lane = tid & 63;
  const int wv = tid >> 6;
  const int e15 = lane & 15;
  const int q = lane >> 4;
  char* hbA = hstage[wv * 2];
  char* hbB = hstage[wv * 2 + 1];

  // ---- one-time staging: fp32 weights -> bf16 A-frags in LDS ----
  // A[m][k] for D = W^T * F: element (k,n) -> lane=((k>>3)&3)*16+(n&15),
  // j=k&7, group g=(k>>5)*8+(n>>4), byte = g*1024 + lane*16 + j*2.
  for (int i = tid; i < 16384; i += 512) {
    int k = i >> 7, n = i & 127;
    int dst = (((k >> 5) * 8 + (n >> 4)) << 10) + ((((k >> 3) & 3) * 16 + (n & 15)) << 4) +
              ((k & 7) << 1);
    *(__bf16*)(wlds[0] + dst) = (__bf16)W1[i];
    *(__bf16*)(wlds[1] + dst) = (__bf16)W2[i];
  }
  if (tid < 128) {
    b1L[tid] = b1[tid];
    b2L[tid] = b2[tid];
    glcL[tid] = (unsigned int)__builtin_bit_cast(unsigned short, (__bf16)lng[tid]) |
                ((unsigned int)__builtin_bit_cast(unsigned short, (__bf16)lnb[tid]) << 16);
  }
  __syncthreads();

  const int ngroups = ntiles >> 1;
  const int nwaves = (gridDim.x * blockDim.x) >> 6;
  const int gwid = (blockIdx.x * blockDim.x + tid) >> 6;

  for (int g = gwid; g < ngroups; g += nwaves) {
    const int t0 = g * 2;
    const int e0 = t0 * 16 + e15;
    const int e1 = e0 + 16;
    const int row0 = eidx[e0];
    const int row1 = eidx[e1];
    int rkA = 0, rkB = 0;
    if constexpr (!ATOMIC) {
      rkA = rank[t0 * 16 + (lane >> 2)];
      rkB = rank[t0 * 16 + 16 + (lane >> 2)];
    }
    const float* x0 = x + (size_t)row0 * 64;
    const float* x1 = x + (size_t)row1 * 64;
    const float* a0 = ea + (size_t)e0 * 64;
    const float* a1 = ea + (size_t)e1 * 64;
    // issue ALL 16 feature loads up front (max memory-level parallelism)
    float4 r0[4][2], r1[4][2];
    r0[0][0] = *(const float4*)(x0 + q * 8);
    r0[0][1] = *(const float4*)(x0 + q * 8 + 4);
    r0[1][0] = *(const float4*)(x0 + 32 + q * 8);
    r0[1][1] = *(const float4*)(x0 + 32 + q * 8 + 4);
    r0[2][0] = *(const float4*)(a0 + q * 8);
    r0[2][1] = *(const float4*)(a0 + q * 8 + 4);
    r0[3][0] = *(const float4*)(a0 + 32 + q * 8);
    r0[3][1] = *(const float4*)(a0 + 32 + q * 8 + 4);
    r1[0][0] = *(const float4*)(x1 + q * 8);
    r1[0][1] = *(const float4*)(x1 + q * 8 + 4);
    r1[1][0] = *(const float4*)(x1 + 32 + q * 8);
    r1[1][1] = *(const float4*)(x1 + 32 + q * 8 + 4);
    r1[2][0] = *(const float4*)(a1 + q * 8);
    r1[2][1] = *(const float4*)(a1 + q * 8 + 4);
    r1[3][0] = *(const float4*)(a1 + 32 + q * 8);
    r1[3][1] = *(const float4*)(a1 + 32 + q * 8 + 4);

    bf16x8 bfr0[4], bfr1[4];
#pragma unroll
    for (int ks = 0; ks < 4; ++ks) {
      const float* p0 = (const float*)&r0[ks][0];
      const float* q1 = (const float*)&r1[ks][0];
#pragma unroll
      for (int j = 0; j < 8; ++j) {
        bfr0[ks][j] = (__bf16)p0[j];
        bfr1[ks][j] = (__bf16)q1[j];
      }
    }

    // ---- GEMM1: c1[mt] rows n=mt*16+q*4+r, cols e ----
    f32x4 c1a[8], c1b[8];
#pragma unroll
    for (int mt = 0; mt < 8; ++mt) {
      f32x4 bv = *(const f32x4*)&b1L[mt * 16 + q * 4];
      c1a[mt] = bv;
      c1b[mt] = bv;
    }
#pragma unroll
    for (int ks = 0; ks < 4; ++ks) {
#pragma unroll
      for (int mt = 0; mt < 8; ++mt) {
        bf16x8 wf = __builtin_bit_cast(
            bf16x8, *(const uint4*)(wlds[0] + ((ks * 8 + mt) << 10) + (lane << 4)));
        c1a[mt] = __builtin_amdgcn_mfma_f32_16x16x32_bf16(wf, bfr0[ks], c1a[mt], 0, 0, 0);
        c1b[mt] = __builtin_amdgcn_mfma_f32_16x16x32_bf16(wf, bfr1[ks], c1b[mt], 0, 0, 0);
      }
    }

    // ---- LayerNorm + ReLU + pack to staging (both tiles) ----
#pragma unroll
    for (int tt = 0; tt < 2; ++tt) {
      f32x4* c1 = tt ? c1b : c1a;
      char* hb = tt ? hbB : hbA;
      float s = 0.f, ss = 0.f;
#pragma unroll
      for (int mt = 0; mt < 8; ++mt)
#pragma unroll
        for (int r = 0; r < 4; ++r) {
          float v = c1[mt][r];
          s += v;
          ss += v * v;
        }
      s += __shfl_xor(s, 16);
      s += __shfl_xor(s, 32);
      ss += __shfl_xor(ss, 16);
      ss += __shfl_xor(ss, 32);
      const float mu = s * 0.0078125f;
      const float var = ss * 0.0078125f - mu * mu;
      const float inv = rsqrtf(var + LN_EPS);
#pragma unroll
      for (int mt = 0; mt < 8; ++mt) {
        uint4 gv = *(const uint4*)&glcL[mt * 16 + q * 4];
        const unsigned int* gp = (const unsigned int*)&gv;
        unsigned short u[4];
#pragma unroll
        for (int r = 0; r < 4; ++r) {
          float v = (c1[mt][r] - mu) * inv;
          v = v * bflo(gp[r]) + bfhi(gp[r]);
          v = fmaxf(v, 0.f);
          u[r] = bfbits(v);
        }
        uint2 w;
        w.x = (unsigned int)u[0] | ((unsigned int)u[1] << 16);
        w.y = (unsigned int)u[2] | ((unsigned int)u[3] << 16);
        *(uint2*)(hb + e15 * 272 + mt * 32 + q * 8) = w;
      }
    }

    // ---- reload as B-frags, GEMM2 ----
    bf16x8 hfa[4], hfb[4];
#pragma unroll
    for (int ks = 0; ks < 4; ++ks) {
      hfa[ks] = __builtin_bit_cast(bf16x8, *(const uint4*)(hbA + e15 * 272 + ks * 64 + q * 16));
      hfb[ks] = __builtin_bit_cast(bf16x8, *(const uint4*)(hbB + e15 * 272 + ks * 64 + q * 16));
    }
    f32x4 c2a[8], c2b[8];
#pragma unroll
    for (int mt = 0; mt < 8; ++mt) {
      f32x4 bv = *(const f32x4*)&b2L[mt * 16 + q * 4];
      c2a[mt] = bv;
      c2b[mt] = bv;
    }
#pragma unroll
    for (int ks = 0; ks < 4; ++ks) {
#pragma unroll
      for (int mt = 0; mt < 8; ++mt) {
        bf16x8 wf = __builtin_bit_cast(
            bf16x8, *(const uint4*)(wlds[1] + ((ks * 8 + mt) << 10) + (lane << 4)));
        c2a[mt] = __builtin_amdgcn_mfma_f32_16x16x32_bf16(wf, hfa[ks], c2a[mt], 0, 0, 0);
        c2b[mt] = __builtin_amdgcn_mfma_f32_16x16x32_bf16(wf, hfb[ks], c2b[mt], 0, 0, 0);
      }
    }

    if constexpr (ATOMIC) {
      const int cl0 = eidx[E + e0];
      const int cl1 = eidx[E + e1];
      float* op0 = out + (size_t)cl0 * 128 + q * 4;
      float* op1 = out + (size_t)cl1 * 128 + q * 4;
#pragma unroll
      for (int mt = 0; mt < 8; ++mt)
#pragma unroll
        for (int r = 0; r < 4; ++r) {
          unsafeAtomicAdd(op0 + mt * 16 + r, c2a[mt][r]);
          unsafeAtomicAdd(op1 + mt * 16 + r, c2b[mt][r]);
        }
    } else {
      // stage bf16 h2 rows, then coalesced 16B stores at CSR rank
#pragma unroll
      for (int tt = 0; tt < 2; ++tt) {
        f32x4* c2 = tt ? c2b : c2a;
        char* hb = tt ? hbB : hbA;
#pragma unroll
        for (int mt = 0; mt < 8; ++mt) {
          unsigned short u[4];
#pragma unroll
          for (int r = 0; r < 4; ++r) u[r] = bfbits(c2[mt][r]);
          uint2 w;
          w.x = (unsigned int)u[0] | ((unsigned int)u[1] << 16);
          w.y = (unsigned int)u[2] | ((unsigned int)u[3] << 16);
          *(uint2*)(hb + e15 * 272 + mt * 32 + q * 8) = w;
        }
      }
      const int sr = lane >> 2, sc = lane & 3;
#pragma unroll
      for (int i = 0; i < 4; ++i) {
        uint4 vA = *(const uint4*)(hbA + sr * 272 + (sc + 4 * i) * 16);
        *(uint4*)((char*)h2 + (size_t)rkA * 256 + (sc + 4 * i) * 16) = vA;
      }
#pragma unroll
      for (int i = 0; i < 4; ++i) {
        uint4 vB = *(const uint4*)(hbB + sr * 272 + (sc + 4 * i) * 16);
        *(uint4*)((char*)h2 + (size_t)rkB * 256 + (sc + 4 * i) * 16) = vB;
      }
    }
  }
}

// ------------------------- segmented mean: one wave per node, streaming rows
__global__ void reduce_kernel(const unsigned short* __restrict__ h2,
                              const int* __restrict__ off, const int* __restrict__ cnt,
                              float* __restrict__ out, int N) {
  const int wv = threadIdx.x >> 6;
  const int lane = threadIdx.x & 63;
  const int node = blockIdx.x * 4 + wv;
  if (node >= N) return;
  const int deg = cnt[node];
  const int start = off[node];
  const unsigned int* p = (const unsigned int*)(h2 + (size_t)start * 128) + lane;
  float a0 = 0.f, a1 = 0.f, b0 = 0.f, b1 = 0.f, c0 = 0.f, c1 = 0.f, d0 = 0.f, d1 = 0.f;
  int j = 0;
  for (; j + 4 <= deg; j += 4) {
    unsigned int u0 = p[0], u1 = p[64], u2 = p[128], u3 = p[192];
    p += 256;
    a0 += bflo(u0);
    a1 += bfhi(u0);
    b0 += bflo(u1);
    b1 += bfhi(u1);
    c0 += bflo(u2);
    c1 += bfhi(u2);
    d0 += bflo(u3);
    d1 += bfhi(u3);
  }
  for (; j < deg; ++j) {
    unsigned int u = p[0];
    p += 64;
    a0 += bflo(u);
    a1 += bfhi(u);
  }
  const float sc = 1.f / (float)(deg > 0 ? deg : 1);
  float2 o;
  o.x = (a0 + b0 + c0 + d0) * sc;
  o.y = (a1 + b1 + c1 + d1) * sc;
  *(float2*)(out + (size_t)node * 128 + lane * 2) = o;
}

// ------------------------------------------------------ divide (atomic path)
__global__ void divide_kernel(float* __restrict__ out, const int* __restrict__ cnt, int N) {
  int i = blockIdx.x * blockDim.x + threadIdx.x;
  if (i >= N * 32) return;
  int node = i >> 5;
  float s = 1.f / (float)(cnt[node] > 0 ? cnt[node] : 1);
  float4* p = (float4*)out + i;
  float4 v = *p;
  v.x *= s;
  v.y *= s;
  v.z *= s;
  v.w *= s;
  *p = v;
}

extern "C" void kernel_launch(void* const* d_in, const int* in_sizes, int n_in,
                              void* d_out, int out_size, void* d_ws, size_t ws_size,
                              hipStream_t stream) {
  const float* x = (const float*)d_in[0];
  const float* ea = (const float*)d_in[1];
  const int* eidx = (const int*)d_in[2];
  const float* W1 = (const float*)d_in[3];
  const float* b1 = (const float*)d_in[4];
  const float* lng = (const float*)d_in[5];
  const float* lnb = (const float*)d_in[6];
  const float* W2 = (const float*)d_in[7];
  const float* b2 = (const float*)d_in[8];
  float* out = (float*)d_out;

  const int N = in_sizes[0] / 64;   // 50000
  const int E = in_sizes[1] / 64;   // 800000
  const int ntiles = E / 16;
  const size_t h2B = (size_t)E * 256;  // bf16 h2 rows
  const size_t rankB = (size_t)E * 4;
  const size_t cB = (size_t)N * 4;
  const size_t need = h2B + rankB + 3 * cB + 4096;
  const int eblocks = (E + 255) / 256;
  const int nScan = (N + 1023) / 1024;

  if (ws_size >= need && nScan <= 64) {
    unsigned short* h2 = (unsigned short*)d_ws;
    char* base = (char*)d_ws + h2B;
    int* rank = (int*)base;
    int* cnt = (int*)(base + rankB);
    int* cur = (int*)(base + rankB + cB);
    int* off = (int*)(base + rankB + 2 * cB);
    int* psum = (int*)(base + rankB + 3 * cB);
    hipMemsetAsync(cnt, 0, 2 * cB, stream);  // cnt + cur contiguous
    hist_kernel<<<eblocks, 256, 0, stream>>>(eidx, cnt, E);
    partial_kernel<<<nScan, 256, 0, stream>>>(cnt, psum, N);
    scanp_kernel<<<1, 64, 0, stream>>>(psum, nScan);
    scanout_kernel<<<nScan, 256, 0, stream>>>(cnt, psum, off, N);
    rank_kernel<<<eblocks, 256, 0, stream>>>(eidx, off, cur, rank, E);
    mlp_kernel<false><<<256, 512, 0, stream>>>(x, ea, eidx, rank, W1, b1, lng, lnb, W2, b2,
                                               out, h2, E, ntiles);
    reduce_kernel<<<(N + 3) / 4, 256, 0, stream>>>(h2, off, cnt, out, N);
  } else {
    // fallback: fused atomic scatter (needs only N*4 bytes of ws)
    int* cnt = (int*)d_ws;
    hipMemsetAsync(out, 0, (size_t)out_size * 4, stream);
    hipMemsetAsync(cnt, 0, cB, stream);
    hist_kernel<<<eblocks, 256, 0, stream>>>(eidx, cnt, E);
    mlp_kernel<true><<<256, 512, 0, stream>>>(x, ea, eidx, nullptr, W1, b1, lng, lnb, W2, b2,
                                              out, (unsigned short*)d_ws, E, ntiles);
    divide_kernel<<<(N * 32 + 255) / 256, 256, 0, stream>>>(out, cnt, N);
  }
}